// Round 4
// baseline (37809.964 us; speedup 1.0000x reference)
//
#include <hip/hip_runtime.h>
#include <math.h>

// LSTM_11089605558768: T=16384 sequential steps, H=512, IN=32, OUT=1.
// Persistent scan, 32 worker wgs x 256 threads, weights resident in regs
// (136 floats/thread = 64x544 slice per wg, [W_hh | W_ih] folded).
//
// R4: XCD-colocation WITHOUT fragile machinery.
//  - 256 blocks launched; workers = blockIdx%8==0 (slot = blockIdx>>3).
//    Under the usual round-robin block->XCD mapping all 32 workers land on
//    XCD 0, one per CU. This is ONLY a speed heuristic.
//  - Exchange packets (tag<<32 | fp32 bits), parity double-buffered.
//    Publish = mirror pair: sc0+sc1 store (LLC, device-visible) THEN sc0
//    store (fresh line in local XCD L2). Poll = sc0 loads (L2-speed when
//    colocated) with an sc0+sc1 LLC refresh every 8th spin. This is
//    deadlock-proof under ANY placement and ANY sc-bit behavior: the LLC
//    mirror always carries the value, the refresh always sees the LLC.
//  - d_ws footprint exactly 8192 B (same as the R2 kernel that passed).
//  - Epilogue: per-gate activation parallelized across all 64 lanes before
//    the shuffle (shorter serial chain than activate-after-gather).

#define T_STEPS 16384
#define IN_DIM  32
#define H_DIM   512
#define SLOTS   32      // worker workgroups
#define GRID    256     // launched blocks; non-workers exit immediately
#define H_SLICE 16      // H_DIM / SLOTS
#define KTOT    544     // H_DIM + IN_DIM
#define CHUNK   136     // KTOT / 4 waves

typedef unsigned int uint32x4 __attribute__((ext_vector_type(4)));

__device__ __forceinline__ float fast_sigmoid(float v) {
  return 1.0f / (1.0f + __expf(-v));
}
__device__ __forceinline__ float fast_tanh(float v) {
  return 2.0f / (1.0f + __expf(-2.0f * v)) - 1.0f;  // 2*sigmoid(2x)-1
}

// --- packet I/O ------------------------------------------------------------
__device__ __forceinline__ void store_pkt_llc(unsigned long long* p,
                                              unsigned long long v) {
  asm volatile("global_store_dwordx2 %0, %1, off sc0 sc1"
               :: "v"(p), "v"(v) : "memory");
}
__device__ __forceinline__ void store_pkt_l2(unsigned long long* p,
                                             unsigned long long v) {
  asm volatile("global_store_dwordx2 %0, %1, off sc0"
               :: "v"(p), "v"(v) : "memory");
}
__device__ __forceinline__ uint32x4 load_pkt2_l2(const unsigned long long* p) {
  uint32x4 r;
  asm volatile("global_load_dwordx4 %0, %1, off sc0\n\ts_waitcnt vmcnt(0)"
               : "=&v"(r) : "v"(p) : "memory");
  return r;
}
__device__ __forceinline__ uint32x4 load_pkt2_llc(const unsigned long long* p) {
  uint32x4 r;
  asm volatile("global_load_dwordx4 %0, %1, off sc0 sc1\n\ts_waitcnt vmcnt(0)"
               : "=&v"(r) : "v"(p) : "memory");
  return r;
}

// Poll two adjacent packets until both carry tag tg; L2-fast with LLC refresh.
__device__ __forceinline__ void poll_pkts(const unsigned long long* p,
                                          unsigned int tg,
                                          float* d0, float* d1) {
  unsigned int spin = 0;
  for (;;) {
    uint32x4 r = ((++spin & 7u) != 0u) ? load_pkt2_l2(p) : load_pkt2_llc(p);
    if (r.y == tg && r.w == tg) {   // [val0, tag0, val1, tag1]
      *d0 = __uint_as_float(r.x);
      *d1 = __uint_as_float(r.z);
      return;
    }
  }
}

__launch_bounds__(256, 1)
__global__ void lstm_scan_kernel(
    const float* __restrict__ x,     // [T, 32]
    const float* __restrict__ Wih,   // [2048, 32]
    const float* __restrict__ Whh,   // [2048, 512]
    const float* __restrict__ bih,   // [2048]
    const float* __restrict__ bhh,   // [2048]
    const float* __restrict__ Wlin,  // [512]
    const float* __restrict__ blin,  // [1]
    float* __restrict__ out,         // [1]
    unsigned long long* pub)         // [2][512] (tag,val) packets in d_ws
{
  const int bx = blockIdx.x;
  if (bx & 7) return;                // non-worker block (placement filler)
  const int slot = bx >> 3;          // 0..31

  const int tid = threadIdx.x;
  const int w   = tid >> 6;   // wave 0..3 -> k-chunk
  const int l   = tid & 63;   // lane -> local gate row

  __shared__ __align__(16) float hshm[KTOT];  // [0,512)=h(t), [512,544)=x_t
  __shared__ float red[256];                  // per-wave partials

  // local row l: 0..15 = i, 16..31 = f, 32..47 = g, 48..63 = o
  const int R = (l >> 4) * H_DIM + slot * H_SLICE + (l & 15);

  // Persistent weight slice -> registers (one-time; latency irrelevant).
  float wreg[CHUNK];
  #pragma unroll
  for (int j = 0; j < CHUNK; ++j) {
    const int k = w * CHUNK + j;
    wreg[j] = (k < H_DIM) ? Whh[R * H_DIM + k]
                          : Wih[R * IN_DIM + (k - H_DIM)];
  }
  const float bias = (w == 0) ? (bih[R] + bhh[R]) : 0.0f;

  float c = 0.0f;  // cell state: wave 0, lanes 0..15 (h index slot*16 + l)

  const int  e0  = tid * 2;               // this thread's 2 h elements
  const bool own = ((tid >> 3) == slot);  // both elements in own slice
  if (own) { hshm[e0] = 0.0f; hshm[e0 + 1] = 0.0f; }  // h(0) = 0 shortcut

  for (int t = 0; t < T_STEPS; ++t) {
    // x_t load overlaps the poll (flag-independent)
    float xv = (tid < IN_DIM) ? x[t * IN_DIM + tid] : 0.0f;

    // ---- gather h(t): poll self-validating packets (tag == t) ----
    if (!own) {
      poll_pkts(pub + (t & 1) * H_DIM + e0, (unsigned int)t,
                &hshm[e0], &hshm[e0 + 1]);
    }
    if (tid < IN_DIM) hshm[H_DIM + tid] = xv;
    __syncthreads();  // barrier B: h(t) + x_t staged

    // ---- matvec: thread (w,l) covers row l, k in [w*136, w*136+136) ----
    const float4* hv = (const float4*)(hshm + w * CHUNK);  // 544B-aligned
    float a0 = 0.f, a1 = 0.f, a2 = 0.f, a3 = 0.f;
    #pragma unroll
    for (int q = 0; q < CHUNK / 4; ++q) {
      const float4 h4 = hv[q];  // wave-uniform broadcast read
      a0 = fmaf(wreg[4 * q + 0], h4.x, a0);
      a1 = fmaf(wreg[4 * q + 1], h4.y, a1);
      a2 = fmaf(wreg[4 * q + 2], h4.z, a2);
      a3 = fmaf(wreg[4 * q + 3], h4.w, a3);
    }
    red[w * 64 + l] = (a0 + a1) + (a2 + a3);
    __syncthreads();  // barrier C: partials ready

    // ---- wave 0: activate (all lanes, parallel), update c/h, publish ----
    if (w == 0) {
      const float g = bias + red[l] + red[64 + l] + red[128 + l] + red[192 + l];
      // lanes 0-15: i (sig), 16-31: f (sig), 32-47: g (tanh), 48-63: o (sig)
      const float act = (l < 32 || l >= 48) ? fast_sigmoid(g) : fast_tanh(g);
      const int j = l & 15;
      const float ig = __shfl(act, j, 64);
      const float fg = __shfl(act, j + 16, 64);
      const float gt = __shfl(act, j + 32, 64);
      const float og = __shfl(act, j + 48, 64);
      if (l < H_SLICE) {
        c = fg * c + ig * gt;
        const float h = og * fast_tanh(c);
        hshm[slot * H_SLICE + l] = h;  // own-slice shortcut for step t+1
        unsigned long long* dst =
            pub + ((t + 1) & 1) * H_DIM + slot * H_SLICE + l;
        const unsigned long long u =
            ((unsigned long long)(unsigned int)(t + 1) << 32) |
            (unsigned long long)__float_as_uint(h);
        store_pkt_llc(dst, u);  // progress guarantee: value always in LLC
        store_pkt_l2(dst, u);   // fast path: fresh line in local XCD L2
      }
    }
    // hshm[own]/red hazards covered by barriers B/C (disjoint index sets).
  }

  // ---- slot 0: final projection out = h(T) . Wlin + blin ----
  if (slot == 0) {
    if (!own) {
      poll_pkts(pub + (T_STEPS & 1) * H_DIM + e0, (unsigned int)T_STEPS,
                &hshm[e0], &hshm[e0 + 1]);
    }
    __syncthreads();
    red[tid] = hshm[e0] * Wlin[e0] + hshm[e0 + 1] * Wlin[e0 + 1];
    __syncthreads();
    if (w == 0) {
      float s = red[l] + red[64 + l] + red[128 + l] + red[192 + l];
      #pragma unroll
      for (int off = 32; off > 0; off >>= 1) s += __shfl_down(s, off, 64);
      if (l == 0) out[0] = s + blin[0];
    }
  }
}

extern "C" void kernel_launch(void* const* d_in, const int* in_sizes, int n_in,
                              void* d_out, int out_size, void* d_ws, size_t ws_size,
                              hipStream_t stream) {
  const float* x    = (const float*)d_in[0];
  const float* Wih  = (const float*)d_in[1];
  const float* Whh  = (const float*)d_in[2];
  const float* bih  = (const float*)d_in[3];
  const float* bhh  = (const float*)d_in[4];
  const float* Wlin = (const float*)d_in[5];
  const float* blin = (const float*)d_in[6];
  float* out = (float*)d_out;

  unsigned long long* pub = (unsigned long long*)d_ws;  // [2][512] u64 = 8KB

  // d_ws re-poisoned 0xAA before every timed call; zeroed pub encodes
  // (tag=0, h=0) == the initial hidden state. Footprint: exactly 8192 B.
  hipMemsetAsync(d_ws, 0, 8192, stream);
  hipLaunchKernelGGL(lstm_scan_kernel, dim3(GRID), dim3(256), 0, stream,
                     x, Wih, Whh, bih, bhh, Wlin, blin, out, pub);
}